// Round 11
// baseline (233.670 us; speedup 1.0000x reference)
//
#include <hip/hip_runtime.h>
#include <math.h>

#define NN 5000
#define NBINS 50
#define BINSZ 100
#define KNN 16
#define BPAD 104          // padded M row length (halves); 208 B stride, 16B aligned
#define NB 20             // nodes per block in MLP kernels

typedef _Float16 half8 __attribute__((ext_vector_type(8)));

__device__ __forceinline__ float lrelu(float x){ return x >= 0.f ? x : 0.01f*x; }

// scatter one packed float4 (chunk element index t, 125-wide rows) into padded
// [row][128] LDS layout.
__device__ __forceinline__ void scatter_w(float* dst, int t, float4 v) {
    int e = 4 * t, r = e / 125, c = e - 125 * r;
    dst[r * 128 + c] = v.x; if (++c == 125) { c = 0; ++r; }
    dst[r * 128 + c] = v.y; if (++c == 125) { c = 0; ++r; }
    dst[r * 128 + c] = v.z; if (++c == 125) { c = 0; ++r; }
    dst[r * 128 + c] = v.w;
}

// =================== fused MLP1 + LSH bin: 250 blocks x 640 thr, 20 nodes/block =====
__global__ __launch_bounds__(640) void nn1_kernel(
    const float* __restrict__ x,
    const float* __restrict__ W1, const float* __restrict__ b1,
    const float* __restrict__ W2, const float* __restrict__ b2,
    const float* __restrict__ W3, const float* __restrict__ b3,
    const float* __restrict__ cb,
    float* __restrict__ h_out, int* __restrict__ bin_idx) {
    __shared__ float sW[8192];        // 2 x 4096 padded [32][128] chunk buffers
    __shared__ float bufX[12 * NB];
    __shared__ float bufA[125 * NB];
    __shared__ float bufB[125 * NB];
    __shared__ float sCB[300];
    int tid = threadIdx.x;
    int n0 = blockIdx.x * NB;         // 250 * 20 = 5000
    int g = tid >> 7, j = tid & 127;  // 5 groups x 128 (125 active) for small layers
    float acc[4];
    float4 r0, r1; float rt = 0.f;

    // ---- stage x (transposed [k][n]), codebook, W1 (packed) ----
    if (tid < 60) {
        float4 v = ((const float4*)(x + n0 * 12))[tid];
        int e = tid * 4;
        bufX[(e % 12) * NB + (e / 12)] = v.x;
        bufX[((e + 1) % 12) * NB + ((e + 1) / 12)] = v.y;
        bufX[((e + 2) % 12) * NB + ((e + 2) / 12)] = v.z;
        bufX[((e + 3) % 12) * NB + ((e + 3) / 12)] = v.w;
    }
    if (tid < 300) { int k = tid / 25, c = tid - k * 25; sCB[tid] = cb[k * 100 + c]; }
    if (tid < 375) ((float4*)sW)[tid] = ((const float4*)W1)[tid];   // 1500 floats
    __syncthreads();

    // ---- L1: 12 -> 125, leaky -> bufA[k][20] ----
    if (j < 125) {
        float bj = b1[j];
        acc[0] = bj; acc[1] = bj; acc[2] = bj; acc[3] = bj;
        #pragma unroll
        for (int k = 0; k < 12; ++k) {
            float w = sW[k * 125 + j];
            float4 a = *(const float4*)&bufX[k * NB + g * 4];
            acc[0] += a.x * w; acc[1] += a.y * w; acc[2] += a.z * w; acc[3] += a.w * w;
        }
        #pragma unroll
        for (int n = 0; n < 4; ++n) bufA[j * NB + g * 4 + n] = lrelu(acc[n]);
    }
    // prefetch W2 chunk0
    r0 = (tid < 1000) ? ((const float4*)W2)[tid] : make_float4(0.f,0.f,0.f,0.f);
    r1 = (tid < 360)  ? ((const float4*)W2)[tid + 640] : make_float4(0.f,0.f,0.f,0.f);
    __syncthreads();
    if (tid < 1000) scatter_w(sW, tid, r0);
    if (tid < 360)  scatter_w(sW, tid + 640, r1);
    __syncthreads();

    // ---- L2: 125 -> 125, chunked dbuf, 4j x 2n register blocking (320 thr) ----
    float acc8[8];
    if (tid < 320) {
        int j4 = tid & 31;
        #pragma unroll
        for (int jj = 0; jj < 4; ++jj) {
            int jc = 4 * j4 + jj;
            float bj = (jc < 125) ? b2[jc] : 0.f;
            acc8[2 * jj] = bj; acc8[2 * jj + 1] = bj;
        }
    }
    for (int c = 0; c < 4; ++c) {
        if (c < 3) {
            int base = (c + 1) * 1000, nf4 = (c + 1 < 3) ? 1000 : 906;
            r0 = (tid < nf4) ? ((const float4*)W2)[base + tid] : make_float4(0.f,0.f,0.f,0.f);
            r1 = (tid + 640 < nf4) ? ((const float4*)W2)[base + tid + 640] : make_float4(0.f,0.f,0.f,0.f);
            if (c + 1 == 3 && tid == 0) rt = W2[15624];
        }
        int nk = (c < 3) ? 32 : 29;
        if (tid < 320) {
            int j4 = tid & 31, n2 = tid >> 5;
            const float* wbuf = sW + (c & 1) * 4096;
            const float* arow = bufA + (c * 32) * NB + 2 * n2;
            for (int k = 0; k < nk; ++k) {
                float4 w4 = *(const float4*)&wbuf[k * 128 + 4 * j4];
                float2 a2 = *(const float2*)&arow[k * NB];
                acc8[0] += w4.x * a2.x; acc8[1] += w4.x * a2.y;
                acc8[2] += w4.y * a2.x; acc8[3] += w4.y * a2.y;
                acc8[4] += w4.z * a2.x; acc8[5] += w4.z * a2.y;
                acc8[6] += w4.w * a2.x; acc8[7] += w4.w * a2.y;
            }
        }
        if (c < 3) {
            float* dst = sW + ((c + 1) & 1) * 4096;
            int nf4 = (c + 1 < 3) ? 1000 : 906;
            if (tid < nf4) scatter_w(dst, tid, r0);
            if (tid + 640 < nf4) scatter_w(dst, tid + 640, r1);
            if (c + 1 == 3 && tid == 0) dst[3708] = rt;   // row 28, col 124
            __syncthreads();
        }
    }
    if (tid < 320) {
        int j4 = tid & 31, n2 = tid >> 5;
        #pragma unroll
        for (int jj = 0; jj < 4; ++jj) {
            int jc = 4 * j4 + jj;
            if (jc < 125) {
                bufB[jc * NB + 2 * n2]     = lrelu(acc8[2 * jj]);
                bufB[jc * NB + 2 * n2 + 1] = lrelu(acc8[2 * jj + 1]);
            }
        }
    }
    __syncthreads();
    if (tid < 375) ((float4*)sW)[tid] = ((const float4*)W3)[tid];   // packed 1500
    __syncthreads();

    // ---- L3: 125 -> 12, 4-way k-split (32/32/32/29) ----
    if (j < 48) {
        int jj = j % 12, s = j / 12;
        int k0 = s * 32, nk = (s < 3) ? 32 : 29;
        float ps[4] = {0.f, 0.f, 0.f, 0.f};
        for (int k = 0; k < nk; ++k) {
            float w = sW[(k0 + k) * 12 + jj];
            float4 a = *(const float4*)&bufB[(k0 + k) * NB + g * 4];
            ps[0] += a.x * w; ps[1] += a.y * w; ps[2] += a.z * w; ps[3] += a.w * w;
        }
        #pragma unroll
        for (int n = 0; n < 4; ++n) bufA[(s * 12 + jj) * NB + g * 4 + n] = ps[n];
    }
    __syncthreads();
    if (tid < 240) {
        int jj = tid / 20, n = tid % 20;
        float v = bufA[jj * NB + n] + bufA[(12 + jj) * NB + n]
                + bufA[(24 + jj) * NB + n] + bufA[(36 + jj) * NB + n] + b3[jj];
        h_out[(n0 + n) * 12 + jj] = v;
        bufB[jj * NB + n] = v;
    }
    __syncthreads();

    // ---- LSH bin (argmax over [mul,-mul], first max wins) ----
    if (tid < NB) {
        int n = tid;
        float hv[12];
        #pragma unroll
        for (int k = 0; k < 12; ++k) hv[k] = bufB[k * NB + n];
        float best = -INFINITY; int bi = 0;
        for (int c = 0; c < 25; ++c) {
            float m = 0.f;
            #pragma unroll
            for (int k = 0; k < 12; ++k) m += hv[k] * sCB[k * 25 + c];
            if (m > best) { best = m; bi = c; }
        }
        for (int c = 0; c < 25; ++c) {
            float m = 0.f;
            #pragma unroll
            for (int k = 0; k < 12; ++k) m += hv[k] * sCB[k * 25 + c];
            if (-m > best) { best = -m; bi = c + 25; }
        }
        bin_idx[n0 + n] = bi;
    }
}

// =================== fused sort + build + convs: 50 blocks x 640 thr ================
// In-block stable counting sort (block p extracts order[100p..100p+100) locally) ->
// kNN (packed-key top16) -> M in LDS -> dis -> hWd -> GCN mm -> GraphConv mm.
// Also does the ygen passthrough.
__global__ __launch_bounds__(640) void graph2_kernel(
    const float* __restrict__ h, const int* __restrict__ bin_idx,
    const float* __restrict__ gcn_W, const float* __restrict__ gcn_b,
    float* __restrict__ gcn_n, float* __restrict__ agg_n,
    const float4* __restrict__ ygen_id4, const float4* __restrict__ ygen4,
    float4* __restrict__ out4) {
    __shared__ _Float16 M[BINSZ * BPAD];       // 20800 B, M[dst][src]
    __shared__ float s_h[BINSZ * 12];
    __shared__ int   s_nodes[BINSZ];
    __shared__ float s_dis[BINSZ];
    __shared__ float s_w[12 * 32];
    __shared__ float s_big[2 * 32 * BPAD];     // aliased: sBI (scan) / s_tv (topk) / hWd|gcn (mm)
    __shared__ int   s_cnt[552];               // cnt[w*50+b] (500) + start[b] (50)
    float* s_hWd = s_big;
    float* s_gcn = s_big + 32 * BPAD;
    int* sBI = (int*)s_big;                    // 5000 ints = 20 KB (fits in 26.6 KB)
    unsigned* s_tv = (unsigned*)s_big;         // 3200 uints during topk
    int p = blockIdx.x, tid = threadIdx.x;

    // stage bin_idx + gcn_W + zero M + ygen passthrough (independent work)
    for (int t = tid; t < NN / 4; t += 640) ((int4*)sBI)[t] = ((const int4*)bin_idx)[t];
    for (int t = tid; t < BINSZ * BPAD / 2; t += 640) ((int*)M)[t] = 0;
    if (tid < 384) s_w[tid] = gcn_W[tid];
    if (tid < 300) {                            // 50 x 300 f4 = 15000
        int gI = p * 300 + tid;
        out4[15000 + gI] = (gI < 7500) ? ygen_id4[gI] : ygen4[gI - 7500];
    }
    __syncthreads();

    // --- pass1: per-(wave-range, bin) histogram. thread t = (w, b): w=t/50, b=t%50 ---
    if (tid < 500) {
        int w = tid / 50, b = tid - 50 * w;
        const int* q = sBI + w * 500;
        int c = 0;
        for (int i = 0; i < 500; ++i) c += (q[i] == b);
        s_cnt[tid] = c;
    }
    __syncthreads();
    if (tid < 50) {                 // total[b]
        int tot = 0;
        for (int w = 0; w < 10; ++w) tot += s_cnt[w * 50 + tid];
        s_cnt[500 + tid] = tot;
    }
    __syncthreads();
    if (tid == 0) {                 // exclusive prefix -> start[b]
        int s = 0;
        for (int b = 0; b < 50; ++b) { int t = s_cnt[500 + b]; s_cnt[500 + b] = s; s += t; }
    }
    __syncthreads();
    // --- pass2: windowed stable scatter into s_nodes (only slots [100p,100p+100)) ---
    if (tid < 500) {
        int w = tid / 50, b = tid - 50 * w;
        int base = s_cnt[500 + b];
        for (int ww = 0; ww < w; ++ww) base += s_cnt[ww * 50 + b];
        int cnt = s_cnt[w * 50 + b];
        int lo = p * BINSZ, hi = lo + BINSZ;
        if (base < hi && base + cnt > lo) {
            const int* q = sBI + w * 500;
            for (int i = 0; i < 500 && base < hi; ++i) {
                if (q[i] == b) {
                    if (base >= lo) s_nodes[base - lo] = w * 500 + i;
                    ++base;
                }
            }
        }
    }
    __syncthreads();

    for (int t = tid; t < BINSZ * 12; t += 640) {
        int i = t / 12, k = t - i * 12;
        s_h[t] = h[s_nodes[i] * 12 + k];
    }
    __syncthreads();

    // --- topk: 200 threads, 50 candidates each, packed keys (tie -> lower j) ---
    // (s_tv overwrites the sBI region; sBI is dead after pass2)
    if (tid < 200) {
        int row = tid >> 1, half = tid & 1;
        const float4* xp = (const float4*)&s_h[row * 12];
        float4 x0 = xp[0], x1 = xp[1], x2 = xp[2];
        unsigned tv[KNN];
        #pragma unroll
        for (int k = 0; k < KNN; ++k) tv[k] = 0u;
        int j0 = half * 50;
        for (int jj = 0; jj < 50; ++jj) {
            int j = j0 + jj;
            const float4* ap = (const float4*)&s_h[j * 12];
            float4 a0 = ap[0], a1 = ap[1], a2 = ap[2];
            float d = x0.x*a0.x + x0.y*a0.y + x0.z*a0.z + x0.w*a0.w
                    + x1.x*a1.x + x1.y*a1.y + x1.z*a1.z + x1.w*a1.w
                    + x2.x*a2.x + x2.y*a2.y + x2.z*a2.z + x2.w*a2.w;
            float v = 1.f / (1.f + expf(-d));
            unsigned key = (__float_as_uint(v) & 0xFFFFFF80u) | (unsigned)(127 - j);
            if (key > tv[KNN - 1]) {
                unsigned ins = key;
                #pragma unroll
                for (int k = 0; k < KNN; ++k) {
                    bool gt = ins > tv[k];
                    unsigned mx = gt ? ins : tv[k];
                    unsigned mn = gt ? tv[k] : ins;
                    tv[k] = mx; ins = mn;
                }
            }
        }
        #pragma unroll
        for (int k = 0; k < KNN; ++k) s_tv[tid * KNN + k] = tv[k];
    }
    __syncthreads();

    // --- merge two sorted 16-lists -> M column tid ---
    if (tid < BINSZ) {
        int base = tid * 32;
        int ia = 0, ib = 0;
        #pragma unroll
        for (int k = 0; k < KNN; ++k) {
            unsigned av = s_tv[base + ia], bv = s_tv[base + 16 + ib];
            bool tA = av > bv;
            unsigned key = tA ? av : bv;
            ia += tA; ib += !tA;
            int ix = 127 - (int)(key & 127u);
            float v = __uint_as_float(key & 0xFFFFFF80u);
            M[ix * BPAD + tid] = (_Float16)v;
        }
    }
    __syncthreads();

    // --- dis = 1/sqrt(1 + rowsum) ---
    if (tid < BINSZ) {
        float dsum = 1.0f;
        #pragma unroll 13
        for (int sc = 0; sc < 13; ++sc) {
            half8 m = *(const half8*)&M[tid * BPAD + sc * 8];
            dsum += (float)m[0] + (float)m[1] + (float)m[2] + (float)m[3]
                  + (float)m[4] + (float)m[5] + (float)m[6] + (float)m[7];
        }
        s_dis[tid] = 1.0f / sqrtf(dsum);
    }
    __syncthreads();

    // --- hWd[cc][s] = dis[s] * (leaky(h[s]) @ W[:,cc]); zero pads for both bufs ---
    for (int o = tid; o < BINSZ * 32; o += 640) {
        int s = o >> 5, cc = o & 31;
        float a = 0.f;
        #pragma unroll
        for (int k = 0; k < 12; ++k) a += lrelu(s_h[s * 12 + k]) * s_w[k * 32 + cc];
        s_hWd[cc * BPAD + s] = s_dis[s] * a;
    }
    if (tid < 128) {
        s_hWd[(tid >> 2) * BPAD + 100 + (tid & 3)] = 0.f;
        s_gcn[(tid >> 2) * BPAD + 100 + (tid & 3)] = 0.f;
    }
    __syncthreads();

    int cc = tid & 31, dgg = tid >> 5;    // dgg in [0,20)
    // --- mm1: gcn[d][cc] = dis[d]*(M@hWd + hWd[d]) + b ---
    {
        float a5[5] = {0.f, 0.f, 0.f, 0.f, 0.f};
        for (int sc = 0; sc < 13; ++sc) {
            float4 hv0 = *(const float4*)&s_hWd[cc * BPAD + sc * 8];
            float4 hv1 = *(const float4*)&s_hWd[cc * BPAD + sc * 8 + 4];
            #pragma unroll
            for (int r = 0; r < 5; ++r) {
                int d = dgg + 20 * r;
                half8 m = *(const half8*)&M[d * BPAD + sc * 8];
                a5[r] += (float)m[0]*hv0.x + (float)m[1]*hv0.y + (float)m[2]*hv0.z + (float)m[3]*hv0.w
                       + (float)m[4]*hv1.x + (float)m[5]*hv1.y + (float)m[6]*hv1.z + (float)m[7]*hv1.w;
            }
        }
        float bc = gcn_b[cc];
        #pragma unroll
        for (int r = 0; r < 5; ++r) {
            int d = dgg + 20 * r;
            float gq = s_dis[d] * (a5[r] + s_hWd[cc * BPAD + d]) + bc;
            s_gcn[cc * BPAD + d] = gq;
            gcn_n[s_nodes[d] * 32 + cc] = gq;
        }
    }
    __syncthreads();
    // --- mm2: agg[d][cc] = M @ gcn ---
    {
        float a5[5] = {0.f, 0.f, 0.f, 0.f, 0.f};
        for (int sc = 0; sc < 13; ++sc) {
            float4 hv0 = *(const float4*)&s_gcn[cc * BPAD + sc * 8];
            float4 hv1 = *(const float4*)&s_gcn[cc * BPAD + sc * 8 + 4];
            #pragma unroll
            for (int r = 0; r < 5; ++r) {
                int d = dgg + 20 * r;
                half8 m = *(const half8*)&M[d * BPAD + sc * 8];
                a5[r] += (float)m[0]*hv0.x + (float)m[1]*hv0.y + (float)m[2]*hv0.z + (float)m[3]*hv0.w
                       + (float)m[4]*hv1.x + (float)m[5]*hv1.y + (float)m[6]*hv1.z + (float)m[7]*hv1.w;
            }
        }
        #pragma unroll
        for (int r = 0; r < 5; ++r) {
            int d = dgg + 20 * r;
            agg_n[s_nodes[d] * 32 + cc] = a5[r];
        }
    }
}

// =================== fused combine + nn2 + nn3: 250 blocks x 640 thr ================
__global__ __launch_bounds__(640) void nn23_kernel(
    const float* __restrict__ gcn_n, const float* __restrict__ agg_n,
    const float* __restrict__ Wrel, const float* __restrict__ brel,
    const float* __restrict__ Wroot,
    const float* __restrict__ A1, const float* __restrict__ ab1,
    const float* __restrict__ A2, const float* __restrict__ ab2,
    const float* __restrict__ A3, const float* __restrict__ ab3,
    const float* __restrict__ B1, const float* __restrict__ bb1,
    const float* __restrict__ B2, const float* __restrict__ bb2,
    const float* __restrict__ B3, const float* __restrict__ bb3,
    float* __restrict__ out_ids, float* __restrict__ out_p4) {
    __shared__ float sW[8192];          // 2 x 4096 padded chunk buffers / arena
    __shared__ float sAG[32 * NB];
    __shared__ float sGC[32 * NB];
    __shared__ float bufC[38 * NB];     // combine out rows 0..31, ids rows 32..37
    __shared__ float bufA[125 * NB];
    __shared__ float bufB[125 * NB];
    int tid = threadIdx.x;
    int n0 = blockIdx.x * NB;
    int g = tid >> 7, j = tid & 127;
    float acc[4];
    float acc8[8];
    float4 r0, r1; float rt = 0.f;

    // ---- stage agg/gcn transposed + Wrel/Wroot + A1 (all concurrent, one sync) ----
    if (tid < 160) {
        float4 va = ((const float4*)(agg_n + n0 * 32))[tid];
        float4 vg = ((const float4*)(gcn_n + n0 * 32))[tid];
        int e = tid * 4, n = e / 32, k = e % 32;
        sAG[k * NB + n] = va.x; sAG[(k+1) * NB + n] = va.y;
        sAG[(k+2) * NB + n] = va.z; sAG[(k+3) * NB + n] = va.w;
        sGC[k * NB + n] = vg.x; sGC[(k+1) * NB + n] = vg.y;
        sGC[(k+2) * NB + n] = vg.z; sGC[(k+3) * NB + n] = vg.w;
    }
    if (tid >= 160 && tid < 416) ((float4*)sW)[tid - 160] = ((const float4*)Wrel)[tid - 160];
    if (tid >= 416 && tid < 640) ((float4*)(sW + 1024))[tid - 416] = ((const float4*)Wroot)[tid - 416];
    if (tid < 32) ((float4*)(sW + 1024))[224 + tid] = ((const float4*)Wroot)[224 + tid];
    for (int t = tid; t < 1000; t += 640) ((float4*)(sW + 2048))[t] = ((const float4*)A1)[t];
    __syncthreads();

    // ---- combine: bufC[jc][n] = leaky(agg@Wrel + brel + gcn@Wroot) ----
    {
        int jc = tid / 20, n = tid % 20;
        float a = brel[jc];
        #pragma unroll 8
        for (int k = 0; k < 32; ++k)
            a += sAG[k * NB + n] * sW[k * 32 + jc] + sGC[k * NB + n] * sW[1024 + k * 32 + jc];
        bufC[jc * NB + n] = lrelu(a);
    }
    __syncthreads();

    // ---- nn2 L1: 32 -> 125 (A1 packed at sW+2048) ----
    if (j < 125) {
        float bj = ab1[j];
        acc[0] = bj; acc[1] = bj; acc[2] = bj; acc[3] = bj;
        #pragma unroll 8
        for (int k = 0; k < 32; ++k) {
            float w = sW[2048 + k * 125 + j];
            float4 a = *(const float4*)&bufC[k * NB + g * 4];
            acc[0] += a.x * w; acc[1] += a.y * w; acc[2] += a.z * w; acc[3] += a.w * w;
        }
        #pragma unroll
        for (int n = 0; n < 4; ++n) bufA[j * NB + g * 4 + n] = lrelu(acc[n]);
    }
    // prefetch A2 chunk0
    r0 = (tid < 1000) ? ((const float4*)A2)[tid] : make_float4(0.f,0.f,0.f,0.f);
    r1 = (tid < 360)  ? ((const float4*)A2)[tid + 640] : make_float4(0.f,0.f,0.f,0.f);
    __syncthreads();
    if (tid < 1000) scatter_w(sW, tid, r0);
    if (tid < 360)  scatter_w(sW, tid + 640, r1);
    __syncthreads();

    // ---- nn2 L2: 125 -> 125, chunked dbuf, 4j x 2n blocking ----
    if (tid < 320) {
        int j4 = tid & 31;
        #pragma unroll
        for (int jj = 0; jj < 4; ++jj) {
            int jc = 4 * j4 + jj;
            float bj = (jc < 125) ? ab2[jc] : 0.f;
            acc8[2 * jj] = bj; acc8[2 * jj + 1] = bj;
        }
    }
    for (int c = 0; c < 4; ++c) {
        if (c < 3) {
            int base = (c + 1) * 1000, nf4 = (c + 1 < 3) ? 1000 : 906;
            r0 = (tid < nf4) ? ((const float4*)A2)[base + tid] : make_float4(0.f,0.f,0.f,0.f);
            r1 = (tid + 640 < nf4) ? ((const float4*)A2)[base + tid + 640] : make_float4(0.f,0.f,0.f,0.f);
            if (c + 1 == 3 && tid == 0) rt = A2[15624];
        }
        int nk = (c < 3) ? 32 : 29;
        if (tid < 320) {
            int j4 = tid & 31, n2 = tid >> 5;
            const float* wbuf = sW + (c & 1) * 4096;
            const float* arow = bufA + (c * 32) * NB + 2 * n2;
            for (int k = 0; k < nk; ++k) {
                float4 w4 = *(const float4*)&wbuf[k * 128 + 4 * j4];
                float2 a2 = *(const float2*)&arow[k * NB];
                acc8[0] += w4.x * a2.x; acc8[1] += w4.x * a2.y;
                acc8[2] += w4.y * a2.x; acc8[3] += w4.y * a2.y;
                acc8[4] += w4.z * a2.x; acc8[5] += w4.z * a2.y;
                acc8[6] += w4.w * a2.x; acc8[7] += w4.w * a2.y;
            }
        }
        if (c < 3) {
            float* dst = sW + ((c + 1) & 1) * 4096;
            int nf4 = (c + 1 < 3) ? 1000 : 906;
            if (tid < nf4) scatter_w(dst, tid, r0);
            if (tid + 640 < nf4) scatter_w(dst, tid + 640, r1);
            if (c + 1 == 3 && tid == 0) dst[3708] = rt;
            __syncthreads();
        }
    }
    if (tid < 320) {
        int j4 = tid & 31, n2 = tid >> 5;
        #pragma unroll
        for (int jj = 0; jj < 4; ++jj) {
            int jc = 4 * j4 + jj;
            if (jc < 125) {
                bufB[jc * NB + 2 * n2]     = lrelu(acc8[2 * jj]);
                bufB[jc * NB + 2 * n2 + 1] = lrelu(acc8[2 * jj + 1]);
            }
        }
    }
    __syncthreads();
    // stage A3 (750 floats -> sW[0..750)) and B1 (4750 floats -> sW[752..5502))
    if (tid < 187) ((float4*)sW)[tid] = ((const float4*)A3)[tid];
    if (tid == 187) { sW[748] = A3[748]; sW[749] = A3[749]; }
    for (int t = tid; t < 1187; t += 640) ((float4*)(sW + 752))[t] = ((const float4*)B1)[t];
    if (tid == 188) { sW[752 + 4748] = B1[4748]; sW[752 + 4749] = B1[4749]; }
    __syncthreads();

    // ---- nn2 L3: 125 -> 6, 4-way k-split ----
    if (j < 24) {
        int jj = j % 6, s = j / 6;
        int k0 = s * 32, nk = (s < 3) ? 32 : 29;
        float ps[4] = {0.f, 0.f, 0.f, 0.f};
        for (int k = 0; k < nk; ++k) {
            float w = sW[(k0 + k) * 6 + jj];
            float4 a = *(const float4*)&bufB[(k0 + k) * NB + g * 4];
            ps[0] += a.x * w; ps[1] += a.y * w; ps[2] += a.z * w; ps[3] += a.w * w;
        }
        #pragma unroll
        for (int n = 0; n < 4; ++n) bufA[(s * 6 + jj) * NB + g * 4 + n] = ps[n];
    }
    __syncthreads();
    if (tid < 120) {
        int jj = tid / 20, n = tid % 20;
        float v = bufA[jj * NB + n] + bufA[(6 + jj) * NB + n]
                + bufA[(12 + jj) * NB + n] + bufA[(18 + jj) * NB + n] + ab3[jj];
        out_ids[(n0 + n) * 6 + jj] = v;
        bufC[(32 + jj) * NB + n] = v;
    }
    __syncthreads();

    // ---- nn3 L1: 38 -> 125 (B1 packed at sW+752) ----
    if (j < 125) {
        float bj = bb1[j];
        acc[0] = bj; acc[1] = bj; acc[2] = bj; acc[3] = bj;
        #pragma unroll 2
        for (int k = 0; k < 38; ++k) {
            float w = sW[752 + k * 125 + j];
            float4 a = *(const float4*)&bufC[k * NB + g * 4];
            acc[0] += a.x * w; acc[1] += a.y * w; acc[2] += a.z * w; acc[3] += a.w * w;
        }
        #pragma unroll
        for (int n = 0; n < 4; ++n) bufA[j * NB + g * 4 + n] = lrelu(acc[n]);
    }
    // prefetch B2 chunk0
    r0 = (tid < 1000) ? ((const float4*)B2)[tid] : make_float4(0.f,0.f,0.f,0.f);
    r1 = (tid < 360)  ? ((const float4*)B2)[tid + 640] : make_float4(0.f,0.f,0.f,0.f);
    __syncthreads();
    if (tid < 1000) scatter_w(sW, tid, r0);
    if (tid < 360)  scatter_w(sW, tid + 640, r1);
    __syncthreads();

    // ---- nn3 L2: 125 -> 125, chunked dbuf, 4j x 2n blocking ----
    if (tid < 320) {
        int j4 = tid & 31;
        #pragma unroll
        for (int jj = 0; jj < 4; ++jj) {
            int jc = 4 * j4 + jj;
            float bj = (jc < 125) ? bb2[jc] : 0.f;
            acc8[2 * jj] = bj; acc8[2 * jj + 1] = bj;
        }
    }
    for (int c = 0; c < 4; ++c) {
        if (c < 3) {
            int base = (c + 1) * 1000, nf4 = (c + 1 < 3) ? 1000 : 906;
            r0 = (tid < nf4) ? ((const float4*)B2)[base + tid] : make_float4(0.f,0.f,0.f,0.f);
            r1 = (tid + 640 < nf4) ? ((const float4*)B2)[base + tid + 640] : make_float4(0.f,0.f,0.f,0.f);
            if (c + 1 == 3 && tid == 0) rt = B2[15624];
        }
        int nk = (c < 3) ? 32 : 29;
        if (tid < 320) {
            int j4 = tid & 31, n2 = tid >> 5;
            const float* wbuf = sW + (c & 1) * 4096;
            const float* arow = bufA + (c * 32) * NB + 2 * n2;
            for (int k = 0; k < nk; ++k) {
                float4 w4 = *(const float4*)&wbuf[k * 128 + 4 * j4];
                float2 a2 = *(const float2*)&arow[k * NB];
                acc8[0] += w4.x * a2.x; acc8[1] += w4.x * a2.y;
                acc8[2] += w4.y * a2.x; acc8[3] += w4.y * a2.y;
                acc8[4] += w4.z * a2.x; acc8[5] += w4.z * a2.y;
                acc8[6] += w4.w * a2.x; acc8[7] += w4.w * a2.y;
            }
        }
        if (c < 3) {
            float* dst = sW + ((c + 1) & 1) * 4096;
            int nf4 = (c + 1 < 3) ? 1000 : 906;
            if (tid < nf4) scatter_w(dst, tid, r0);
            if (tid + 640 < nf4) scatter_w(dst, tid + 640, r1);
            if (c + 1 == 3 && tid == 0) dst[3708] = rt;
            __syncthreads();
        }
    }
    if (tid < 320) {
        int j4 = tid & 31, n2 = tid >> 5;
        #pragma unroll
        for (int jj = 0; jj < 4; ++jj) {
            int jc = 4 * j4 + jj;
            if (jc < 125) {
                bufB[jc * NB + 2 * n2]     = lrelu(acc8[2 * jj]);
                bufB[jc * NB + 2 * n2 + 1] = lrelu(acc8[2 * jj + 1]);
            }
        }
    }
    __syncthreads();
    // stage B3 (750 floats, packed)
    if (tid < 187) ((float4*)sW)[tid] = ((const float4*)B3)[tid];
    if (tid == 187) { sW[748] = B3[748]; sW[749] = B3[749]; }
    __syncthreads();

    // ---- nn3 L3: 125 -> 6, 4-way k-split ----
    if (j < 24) {
        int jj = j % 6, s = j / 6;
        int k0 = s * 32, nk = (s < 3) ? 32 : 29;
        float ps[4] = {0.f, 0.f, 0.f, 0.f};
        for (int k = 0; k < nk; ++k) {
            float w = sW[(k0 + k) * 6 + jj];
            float4 a = *(const float4*)&bufB[(k0 + k) * NB + g * 4];
            ps[0] += a.x * w; ps[1] += a.y * w; ps[2] += a.z * w; ps[3] += a.w * w;
        }
        #pragma unroll
        for (int n = 0; n < 4; ++n) bufA[(s * 6 + jj) * NB + g * 4 + n] = ps[n];
    }
    __syncthreads();
    if (tid < 120) {
        int jj = tid / 20, n = tid % 20;
        float v = bufA[jj * NB + n] + bufA[(6 + jj) * NB + n]
                + bufA[(12 + jj) * NB + n] + bufA[(18 + jj) * NB + n] + bb3[jj];
        out_p4[(n0 + n) * 6 + jj] = v;
    }
}

static inline int cdiv(int a, int b) { return (a + b - 1) / b; }

extern "C" void kernel_launch(void* const* d_in, const int* in_sizes, int n_in,
                              void* d_out, int out_size, void* d_ws, size_t ws_size,
                              hipStream_t stream) {
    const float* x        = (const float*)d_in[0];
    const float* ygen_id  = (const float*)d_in[1];
    const float* ygen     = (const float*)d_in[2];
    const float* codebook = (const float*)d_in[3];
    const float* nn1_W1 = (const float*)d_in[4];  const float* nn1_b1 = (const float*)d_in[5];
    const float* nn1_W2 = (const float*)d_in[6];  const float* nn1_b2 = (const float*)d_in[7];
    const float* nn1_W3 = (const float*)d_in[8];  const float* nn1_b3 = (const float*)d_in[9];
    const float* gcn_W  = (const float*)d_in[10]; const float* gcn_b  = (const float*)d_in[11];
    const float* gc_Wrel = (const float*)d_in[12]; const float* gc_brel = (const float*)d_in[13];
    const float* gc_Wroot = (const float*)d_in[14];
    const float* nn2_W1 = (const float*)d_in[15]; const float* nn2_b1 = (const float*)d_in[16];
    const float* nn2_W2 = (const float*)d_in[17]; const float* nn2_b2 = (const float*)d_in[18];
    const float* nn2_W3 = (const float*)d_in[19]; const float* nn2_b3 = (const float*)d_in[20];
    const float* nn3_W1 = (const float*)d_in[21]; const float* nn3_b1 = (const float*)d_in[22];
    const float* nn3_W2 = (const float*)d_in[23]; const float* nn3_b2 = (const float*)d_in[24];
    const float* nn3_W3 = (const float*)d_in[25]; const float* nn3_b3 = (const float*)d_in[26];

    float* out = (float*)d_out;
    float* ws  = (float*)d_ws;

    float* h      = ws + 0;         // 60000
    float* gcn_n  = ws + 60000;     // 160000
    float* agg_n  = ws + 220000;    // 160000
    int* bin_idx  = (int*)(ws + 380000);        // 5000

    nn1_kernel<<<NN / NB, 640, 0, stream>>>(
        x, nn1_W1, nn1_b1, nn1_W2, nn1_b2, nn1_W3, nn1_b3, codebook,
        h, bin_idx);

    graph2_kernel<<<NBINS, 640, 0, stream>>>(
        h, bin_idx, gcn_W, gcn_b, gcn_n, agg_n,
        (const float4*)ygen_id, (const float4*)ygen, (float4*)out);

    nn23_kernel<<<NN / NB, 640, 0, stream>>>(
        gcn_n, agg_n, gc_Wrel, gc_brel, gc_Wroot,
        nn2_W1, nn2_b1, nn2_W2, nn2_b2, nn2_W3, nn2_b3,
        nn3_W1, nn3_b1, nn3_W2, nn3_b2, nn3_W3, nn3_b3,
        out, out + 30000);
}

// Round 12
// 196.215 us; speedup vs baseline: 1.1909x; 1.1909x over previous
//
#include <hip/hip_runtime.h>
#include <math.h>

#define NN 5000
#define NBINS 50
#define BINSZ 100
#define KNN 16
#define BPAD 104          // padded M row length (halves); 208 B stride, 16B aligned
#define MROWS 112         // padded row count in conv kernel
#define NB 20             // nodes per block in MLP kernels (5 groups x 4)

typedef _Float16 half8 __attribute__((ext_vector_type(8)));

__device__ __forceinline__ float lrelu(float x){ return x >= 0.f ? x : 0.01f*x; }

// =================== fused MLP1 + LSH bin: 250 blocks x 640 thr, 20 nodes/block =====
__global__ __launch_bounds__(640) void nn1_kernel(
    const float* __restrict__ x,
    const float* __restrict__ W1, const float* __restrict__ b1,
    const float* __restrict__ W2, const float* __restrict__ b2,
    const float* __restrict__ W3, const float* __restrict__ b3,
    const float* __restrict__ cb,
    float* __restrict__ h_out, int* __restrict__ bin_idx) {
    __shared__ float sW[8000];        // 2 x 4000 (32x125) chunk buffers
    __shared__ float bufX[12 * NB];
    __shared__ float bufA[125 * NB];
    __shared__ float bufB[125 * NB];
    __shared__ float sCB[300];
    int tid = threadIdx.x;
    int n0 = blockIdx.x * NB;         // 250 * 20 = 5000
    int g = tid >> 7, j = tid & 127;  // 5 groups x 128 (125 active)
    float acc[4];
    float4 r0, r1; float rt = 0.f;

    // ---- stage x (transposed [k][n]), codebook, W1 ----
    if (tid < 60) {
        float4 v = ((const float4*)(x + n0 * 12))[tid];
        int e = tid * 4;
        bufX[(e % 12) * NB + (e / 12)] = v.x;
        bufX[((e + 1) % 12) * NB + ((e + 1) / 12)] = v.y;
        bufX[((e + 2) % 12) * NB + ((e + 2) / 12)] = v.z;
        bufX[((e + 3) % 12) * NB + ((e + 3) / 12)] = v.w;
    }
    if (tid < 300) { int k = tid / 25, c = tid - k * 25; sCB[tid] = cb[k * 100 + c]; }
    if (tid < 375) ((float4*)sW)[tid] = ((const float4*)W1)[tid];   // 1500 floats
    __syncthreads();

    // ---- L1: 12 -> 125, leaky -> bufA[k][20] ----
    if (j < 125) {
        float bj = b1[j];
        acc[0] = bj; acc[1] = bj; acc[2] = bj; acc[3] = bj;
        #pragma unroll
        for (int k = 0; k < 12; ++k) {
            float w = sW[k * 125 + j];
            float4 a = *(const float4*)&bufX[k * NB + g * 4];
            acc[0] += a.x * w; acc[1] += a.y * w; acc[2] += a.z * w; acc[3] += a.w * w;
        }
        #pragma unroll
        for (int n = 0; n < 4; ++n) bufA[j * NB + g * 4 + n] = lrelu(acc[n]);
    }
    // prefetch W2 chunk0 (1000 float4: [tid] + [tid+640] halves)
    r0 = (tid < 1000) ? ((const float4*)W2)[tid] : make_float4(0.f,0.f,0.f,0.f);
    r1 = (tid < 360)  ? ((const float4*)W2)[tid + 640] : make_float4(0.f,0.f,0.f,0.f);
    __syncthreads();
    if (tid < 1000) ((float4*)sW)[tid] = r0;
    if (tid < 360)  ((float4*)sW)[tid + 640] = r1;
    __syncthreads();

    // ---- L2: 125 -> 125, chunked (32/32/32/29 rows), reg-prefetch dbuf ----
    if (j < 125) { float bj = b2[j]; acc[0] = bj; acc[1] = bj; acc[2] = bj; acc[3] = bj; }
    for (int c = 0; c < 4; ++c) {
        if (c < 3) {
            int base = (c + 1) * 1000, nf4 = (c + 1 < 3) ? 1000 : 906;
            r0 = (tid < nf4) ? ((const float4*)W2)[base + tid] : make_float4(0.f,0.f,0.f,0.f);
            r1 = (tid + 640 < nf4) ? ((const float4*)W2)[base + tid + 640] : make_float4(0.f,0.f,0.f,0.f);
            if (c + 1 == 3 && tid == 0) rt = W2[15624];
        }
        int nk = (c < 3) ? 32 : 29;
        const float* wbuf = sW + (c & 1) * 4000;
        if (j < 125) {
            const float* arow = &bufA[(c * 32) * NB + g * 4];
            for (int k = 0; k < nk; ++k) {
                float w = wbuf[k * 125 + j];
                float4 a = *(const float4*)&arow[k * NB];
                acc[0] += a.x * w; acc[1] += a.y * w; acc[2] += a.z * w; acc[3] += a.w * w;
            }
        }
        if (c < 3) {
            float* dst = sW + ((c + 1) & 1) * 4000;
            int nf4 = (c + 1 < 3) ? 1000 : 906;
            if (tid < nf4) ((float4*)dst)[tid] = r0;
            if (tid + 640 < nf4) ((float4*)dst)[tid + 640] = r1;
            if (c + 1 == 3 && tid == 0) dst[3624] = rt;
            __syncthreads();
        }
    }
    if (j < 125) {
        #pragma unroll
        for (int n = 0; n < 4; ++n) bufB[j * NB + g * 4 + n] = lrelu(acc[n]);
    }
    // stage W3 (375 float4 -> buf0; chunk3 compute used buf1, disjoint)
    __syncthreads();
    if (tid < 375) ((float4*)sW)[tid] = ((const float4*)W3)[tid];
    __syncthreads();

    // ---- L3: 125 -> 12, 4-way k-split (32/32/32/29) ----
    if (j < 48) {
        int jj = j % 12, s = j / 12;
        int k0 = s * 32, nk = (s < 3) ? 32 : 29;
        float ps[4] = {0.f, 0.f, 0.f, 0.f};
        for (int k = 0; k < nk; ++k) {
            float w = sW[(k0 + k) * 12 + jj];
            float4 a = *(const float4*)&bufB[(k0 + k) * NB + g * 4];
            ps[0] += a.x * w; ps[1] += a.y * w; ps[2] += a.z * w; ps[3] += a.w * w;
        }
        #pragma unroll
        for (int n = 0; n < 4; ++n) bufA[(s * 12 + jj) * NB + g * 4 + n] = ps[n];
    }
    __syncthreads();
    if (tid < 240) {
        int jj = tid / 20, n = tid % 20;
        float v = bufA[jj * NB + n] + bufA[(12 + jj) * NB + n]
                + bufA[(24 + jj) * NB + n] + bufA[(36 + jj) * NB + n] + b3[jj];
        h_out[(n0 + n) * 12 + jj] = v;
        bufB[jj * NB + n] = v;
    }
    __syncthreads();

    // ---- LSH bin (argmax over [mul,-mul], first max wins) ----
    if (tid < NB) {
        int n = tid;
        float hv[12];
        #pragma unroll
        for (int k = 0; k < 12; ++k) hv[k] = bufB[k * NB + n];
        float best = -INFINITY; int bi = 0;
        for (int c = 0; c < 25; ++c) {
            float m = 0.f;
            #pragma unroll
            for (int k = 0; k < 12; ++k) m += hv[k] * sCB[k * 25 + c];
            if (m > best) { best = m; bi = c; }
        }
        for (int c = 0; c < 25; ++c) {
            float m = 0.f;
            #pragma unroll
            for (int k = 0; k < 12; ++k) m += hv[k] * sCB[k * 25 + c];
            if (-m > best) { best = -m; bi = c + 25; }
        }
        bin_idx[n0 + n] = bi;
    }
}

// =================== stable argsort-by-bin (LDS-staged) =============================
__global__ __launch_bounds__(64) void scatter_kernel(
    const int* __restrict__ bin_idx, int* __restrict__ order) {
    __shared__ int sBI[NN];
    int b = blockIdx.x, lane = threadIdx.x;
    for (int t = lane; t < NN / 4; t += 64) ((int4*)sBI)[t] = ((const int4*)bin_idx)[t];
    __syncthreads();
    unsigned long long below = (lane == 0) ? 0ULL : ((~0ULL) >> (64 - lane));
    int cnt_lt = 0;
    for (int base = 0; base < NN; base += 64) {
        int i = base + lane;
        int bi = (i < NN) ? sBI[i] : 999;
        cnt_lt += __popcll(__ballot(bi < b));
    }
    int offs = cnt_lt;
    for (int base = 0; base < NN; base += 64) {
        int i = base + lane;
        int bi = (i < NN) ? sBI[i] : 999;
        unsigned long long m = __ballot(bi == b);
        if (bi == b) order[offs + __popcll(m & below)] = i;
        offs += __popcll(m);
    }
}

// =================== K1: build dense fp16 edge matrix M + dis (50 blocks) ===========
// Packed-key top-16: key = (sigmoid_bits & ~0x7F) | (127 - j)  -> tie-break embedded.
__global__ __launch_bounds__(256) void build_kernel(
    const float* __restrict__ h, const int* __restrict__ order,
    _Float16* __restrict__ Mg, float* __restrict__ dis_g) {
    __shared__ _Float16 M[BINSZ * BPAD];
    __shared__ float s_h[BINSZ * 12];
    __shared__ int   s_nodes[BINSZ];
    __shared__ unsigned s_tv[200 * KNN];     // 12.8 KB packed keys
    int p = blockIdx.x, tid = threadIdx.x;

    if (tid < BINSZ) s_nodes[tid] = order[p * BINSZ + tid];
    for (int t = tid; t < BINSZ * BPAD / 2; t += 256) ((int*)M)[t] = 0;
    __syncthreads();
    for (int t = tid; t < BINSZ * 12; t += 256) {
        int i = t / 12, k = t - i * 12;
        s_h[t] = h[s_nodes[i] * 12 + k];
    }
    __syncthreads();

    // local top-16 over 50 candidates (row = tid>>1, half = tid&1), packed keys
    if (tid < 200) {
        int row = tid >> 1, half = tid & 1;
        const float4* xp = (const float4*)&s_h[row * 12];
        float4 x0 = xp[0], x1 = xp[1], x2 = xp[2];
        unsigned tv[KNN];
        #pragma unroll
        for (int k = 0; k < KNN; ++k) tv[k] = 0u;
        int j0 = half * 50;
        for (int jj = 0; jj < 50; ++jj) {
            int j = j0 + jj;
            const float4* ap = (const float4*)&s_h[j * 12];
            float4 a0 = ap[0], a1 = ap[1], a2 = ap[2];
            float d = x0.x*a0.x + x0.y*a0.y + x0.z*a0.z + x0.w*a0.w
                    + x1.x*a1.x + x1.y*a1.y + x1.z*a1.z + x1.w*a1.w
                    + x2.x*a2.x + x2.y*a2.y + x2.z*a2.z + x2.w*a2.w;
            float v = 1.f / (1.f + expf(-d));
            unsigned key = (__float_as_uint(v) & 0xFFFFFF80u) | (unsigned)(127 - j);
            if (key > tv[KNN - 1]) {
                unsigned ins = key;
                #pragma unroll
                for (int k = 0; k < KNN; ++k) {
                    bool gt = ins > tv[k];
                    unsigned mx = gt ? ins : tv[k];
                    unsigned mn = gt ? tv[k] : ins;
                    tv[k] = mx; ins = mn;
                }
            }
        }
        #pragma unroll
        for (int k = 0; k < KNN; ++k) s_tv[tid * KNN + k] = tv[k];
    }
    __syncthreads();

    // merge two sorted 16-lists (keys embed tie-break; equality impossible)
    if (tid < BINSZ) {
        int base = tid * 32;
        int ia = 0, ib = 0;
        #pragma unroll
        for (int k = 0; k < KNN; ++k) {
            unsigned av = s_tv[base + ia], bv = s_tv[base + 16 + ib];
            bool tA = av > bv;
            unsigned key = tA ? av : bv;
            ia += tA; ib += !tA;
            int ix = 127 - (int)(key & 127u);
            float v = __uint_as_float(key & 0xFFFFFF80u);
            M[ix * BPAD + tid] = (_Float16)v;    // edge tid -> ix
        }
    }
    __syncthreads();

    for (int t = tid; t < BINSZ * BPAD / 8; t += 256)
        ((uint4*)(Mg + (size_t)p * BINSZ * BPAD))[t] = ((const uint4*)M)[t];
    if (tid < BINSZ) {
        float dsum = 1.0f;
        #pragma unroll 13
        for (int sc = 0; sc < 13; ++sc) {
            half8 m = *(const half8*)&M[tid * BPAD + sc * 8];
            dsum += (float)m[0] + (float)m[1] + (float)m[2] + (float)m[3]
                  + (float)m[4] + (float)m[5] + (float)m[6] + (float)m[7];
        }
        dis_g[p * BINSZ + tid] = 1.0f / sqrtf(dsum);
    }
}

// =================== K2: channel-sliced convs (200 blocks) + ygen passthrough =======
__global__ __launch_bounds__(128) void conv_kernel(
    const _Float16* __restrict__ Mg, const float* __restrict__ dis_g,
    const float* __restrict__ h, const int* __restrict__ order,
    const float* __restrict__ gcn_W, const float* __restrict__ gcn_b,
    float* __restrict__ gcn_n, float* __restrict__ agg_n,
    const float4* __restrict__ ygen_id4, const float4* __restrict__ ygen4,
    float4* __restrict__ out4) {
    __shared__ _Float16 M[MROWS * BPAD];
    __shared__ float s_h[BINSZ * 12];
    __shared__ int   s_nodes[BINSZ];
    __shared__ float s_dis[BINSZ];
    __shared__ float s_w[12 * 8];
    __shared__ float s_hWd[8 * BPAD];
    __shared__ float s_gcn[8 * BPAD];
    int bid = blockIdx.x, tid = threadIdx.x;
    int p = bid >> 2, cg = bid & 3, c0 = cg * 8;

    // passthrough: 200 blocks x 75 float4 = 15000 exactly
    if (tid < 75) {
        int gI = bid * 75 + tid;
        out4[15000 + gI] = (gI < 7500) ? ygen_id4[gI] : ygen4[gI - 7500];
    }
    if (tid < BINSZ) {
        s_nodes[tid] = order[p * BINSZ + tid];
        s_dis[tid]   = dis_g[p * BINSZ + tid];
    }
    for (int t = tid; t < 96; t += 128)
        s_w[t] = gcn_W[(t >> 3) * 32 + c0 + (t & 7)];
    for (int t = tid; t < BINSZ * BPAD / 8; t += 128)
        ((uint4*)M)[t] = ((const uint4*)(Mg + (size_t)p * BINSZ * BPAD))[t];
    for (int t = tid; t < (MROWS - BINSZ) * BPAD / 2; t += 128)
        ((int*)(M + BINSZ * BPAD))[t] = 0;
    if (tid < 32) {
        s_hWd[(tid >> 2) * BPAD + 100 + (tid & 3)] = 0.f;
        s_gcn[(tid >> 2) * BPAD + 100 + (tid & 3)] = 0.f;
    }
    __syncthreads();
    for (int t = tid; t < BINSZ * 12; t += 128) {
        int i = t / 12, k = t - i * 12;
        s_h[t] = h[s_nodes[i] * 12 + k];
    }
    __syncthreads();

    for (int o = tid; o < BINSZ * 8; o += 128) {
        int s = o >> 3, cc = o & 7;
        float a = 0.f;
        #pragma unroll
        for (int k = 0; k < 12; ++k) a += lrelu(s_h[s * 12 + k]) * s_w[k * 8 + cc];
        s_hWd[cc * BPAD + s] = s_dis[s] * a;
    }
    __syncthreads();

    int cc = tid & 7, dg = tid >> 3;
    {
        float acc[7];
        #pragma unroll
        for (int r = 0; r < 7; ++r) acc[r] = 0.f;
        for (int sc = 0; sc < 13; ++sc) {
            float4 hv0 = *(const float4*)&s_hWd[cc * BPAD + sc * 8];
            float4 hv1 = *(const float4*)&s_hWd[cc * BPAD + sc * 8 + 4];
            #pragma unroll
            for (int r = 0; r < 7; ++r) {
                int d = dg + 16 * r;
                half8 m = *(const half8*)&M[d * BPAD + sc * 8];
                acc[r] += (float)m[0]*hv0.x + (float)m[1]*hv0.y + (float)m[2]*hv0.z + (float)m[3]*hv0.w
                        + (float)m[4]*hv1.x + (float)m[5]*hv1.y + (float)m[6]*hv1.z + (float)m[7]*hv1.w;
            }
        }
        float bc = gcn_b[c0 + cc];
        #pragma unroll
        for (int r = 0; r < 7; ++r) {
            int d = dg + 16 * r;
            if (d < BINSZ) {
                float gq = s_dis[d] * (acc[r] + s_hWd[cc * BPAD + d]) + bc;
                s_gcn[cc * BPAD + d] = gq;
                gcn_n[s_nodes[d] * 32 + c0 + cc] = gq;
            }
        }
    }
    __syncthreads();
    {
        float acc[7];
        #pragma unroll
        for (int r = 0; r < 7; ++r) acc[r] = 0.f;
        for (int sc = 0; sc < 13; ++sc) {
            float4 hv0 = *(const float4*)&s_gcn[cc * BPAD + sc * 8];
            float4 hv1 = *(const float4*)&s_gcn[cc * BPAD + sc * 8 + 4];
            #pragma unroll
            for (int r = 0; r < 7; ++r) {
                int d = dg + 16 * r;
                half8 m = *(const half8*)&M[d * BPAD + sc * 8];
                acc[r] += (float)m[0]*hv0.x + (float)m[1]*hv0.y + (float)m[2]*hv0.z + (float)m[3]*hv0.w
                        + (float)m[4]*hv1.x + (float)m[5]*hv1.y + (float)m[6]*hv1.z + (float)m[7]*hv1.w;
            }
        }
        #pragma unroll
        for (int r = 0; r < 7; ++r) {
            int d = dg + 16 * r;
            if (d < BINSZ) agg_n[s_nodes[d] * 32 + c0 + cc] = acc[r];
        }
    }
}

// =================== fused combine + nn2 + nn3: 250 blocks x 640 thr ================
__global__ __launch_bounds__(640) void nn23_kernel(
    const float* __restrict__ gcn_n, const float* __restrict__ agg_n,
    const float* __restrict__ Wrel, const float* __restrict__ brel,
    const float* __restrict__ Wroot,
    const float* __restrict__ A1, const float* __restrict__ ab1,
    const float* __restrict__ A2, const float* __restrict__ ab2,
    const float* __restrict__ A3, const float* __restrict__ ab3,
    const float* __restrict__ B1, const float* __restrict__ bb1,
    const float* __restrict__ B2, const float* __restrict__ bb2,
    const float* __restrict__ B3, const float* __restrict__ bb3,
    float* __restrict__ out_ids, float* __restrict__ out_p4) {
    __shared__ float sW[8000];          // layout phase1: Wrel[0..1024) Wroot[1024..2048) A1[2048..6048)
    __shared__ float sAG[32 * NB];      // [k][n]
    __shared__ float sGC[32 * NB];
    __shared__ float bufC[38 * NB];     // combine out rows 0..31, ids rows 32..37
    __shared__ float bufA[125 * NB];
    __shared__ float bufB[125 * NB];
    int tid = threadIdx.x;
    int n0 = blockIdx.x * NB;
    int g = tid >> 7, j = tid & 127;
    float acc[4];
    float4 r0, r1; float rt = 0.f;

    // ---- stage agg/gcn transposed + Wrel/Wroot + A1 (all concurrent, one sync) ----
    if (tid < 160) {
        float4 va = ((const float4*)(agg_n + n0 * 32))[tid];
        float4 vg = ((const float4*)(gcn_n + n0 * 32))[tid];
        int e = tid * 4, n = e / 32, k = e % 32;
        sAG[k * NB + n] = va.x; sAG[(k+1) * NB + n] = va.y;
        sAG[(k+2) * NB + n] = va.z; sAG[(k+3) * NB + n] = va.w;
        sGC[k * NB + n] = vg.x; sGC[(k+1) * NB + n] = vg.y;
        sGC[(k+2) * NB + n] = vg.z; sGC[(k+3) * NB + n] = vg.w;
    }
    if (tid >= 160 && tid < 416) ((float4*)sW)[tid - 160] = ((const float4*)Wrel)[tid - 160];
    if (tid >= 416 && tid < 640) ((float4*)(sW + 1024))[tid - 416] = ((const float4*)Wroot)[tid - 416];
    if (tid < 32) ((float4*)(sW + 1024))[224 + tid] = ((const float4*)Wroot)[224 + tid];
    for (int t = tid; t < 1000; t += 640) ((float4*)(sW + 2048))[t] = ((const float4*)A1)[t];
    __syncthreads();

    // ---- combine: bufC[jc][n] = leaky(agg@Wrel + brel + gcn@Wroot), 32x20=640 thr ---
    {
        int jc = tid / 20, n = tid % 20;
        float a = brel[jc];
        #pragma unroll 8
        for (int k = 0; k < 32; ++k)
            a += sAG[k * NB + n] * sW[k * 32 + jc] + sGC[k * NB + n] * sW[1024 + k * 32 + jc];
        bufC[jc * NB + n] = lrelu(a);
    }
    __syncthreads();

    // ---- nn2 L1: 32 -> 125 (A1 at sW+2048) ----
    if (j < 125) {
        float bj = ab1[j];
        acc[0] = bj; acc[1] = bj; acc[2] = bj; acc[3] = bj;
        #pragma unroll 8
        for (int k = 0; k < 32; ++k) {
            float w = sW[2048 + k * 125 + j];
            float4 a = *(const float4*)&bufC[k * NB + g * 4];
            acc[0] += a.x * w; acc[1] += a.y * w; acc[2] += a.z * w; acc[3] += a.w * w;
        }
        #pragma unroll
        for (int n = 0; n < 4; ++n) bufA[j * NB + g * 4 + n] = lrelu(acc[n]);
    }
    // prefetch A2 chunk0
    r0 = (tid < 1000) ? ((const float4*)A2)[tid] : make_float4(0.f,0.f,0.f,0.f);
    r1 = (tid < 360)  ? ((const float4*)A2)[tid + 640] : make_float4(0.f,0.f,0.f,0.f);
    __syncthreads();
    if (tid < 1000) ((float4*)sW)[tid] = r0;
    if (tid < 360)  ((float4*)sW)[tid + 640] = r1;
    __syncthreads();

    // ---- nn2 L2: 125 -> 125, chunked dbuf ----
    if (j < 125) { float bj = ab2[j]; acc[0] = bj; acc[1] = bj; acc[2] = bj; acc[3] = bj; }
    for (int c = 0; c < 4; ++c) {
        if (c < 3) {
            int base = (c + 1) * 1000, nf4 = (c + 1 < 3) ? 1000 : 906;
            r0 = (tid < nf4) ? ((const float4*)A2)[base + tid] : make_float4(0.f,0.f,0.f,0.f);
            r1 = (tid + 640 < nf4) ? ((const float4*)A2)[base + tid + 640] : make_float4(0.f,0.f,0.f,0.f);
            if (c + 1 == 3 && tid == 0) rt = A2[15624];
        }
        int nk = (c < 3) ? 32 : 29;
        const float* wbuf = sW + (c & 1) * 4000;
        if (j < 125) {
            const float* arow = &bufA[(c * 32) * NB + g * 4];
            for (int k = 0; k < nk; ++k) {
                float w = wbuf[k * 125 + j];
                float4 a = *(const float4*)&arow[k * NB];
                acc[0] += a.x * w; acc[1] += a.y * w; acc[2] += a.z * w; acc[3] += a.w * w;
            }
        }
        if (c < 3) {
            float* dst = sW + ((c + 1) & 1) * 4000;
            int nf4 = (c + 1 < 3) ? 1000 : 906;
            if (tid < nf4) ((float4*)dst)[tid] = r0;
            if (tid + 640 < nf4) ((float4*)dst)[tid + 640] = r1;
            if (c + 1 == 3 && tid == 0) dst[3624] = rt;
            __syncthreads();
        }
    }
    if (j < 125) {
        #pragma unroll
        for (int n = 0; n < 4; ++n) bufB[j * NB + g * 4 + n] = lrelu(acc[n]);
    }
    __syncthreads();
    // stage A3 (750 floats -> sW[0..750)) and B1 (4750 floats -> sW[752..5502))
    if (tid < 187) ((float4*)sW)[tid] = ((const float4*)A3)[tid];
    if (tid == 187) { sW[748] = A3[748]; sW[749] = A3[749]; }
    for (int t = tid; t < 1187; t += 640) ((float4*)(sW + 752))[t] = ((const float4*)B1)[t];
    if (tid == 188) { sW[752 + 4748] = B1[4748]; sW[752 + 4749] = B1[4749]; }
    __syncthreads();

    // ---- nn2 L3: 125 -> 6, 4-way k-split ----
    if (j < 24) {
        int jj = j % 6, s = j / 6;
        int k0 = s * 32, nk = (s < 3) ? 32 : 29;
        float ps[4] = {0.f, 0.f, 0.f, 0.f};
        for (int k = 0; k < nk; ++k) {
            float w = sW[(k0 + k) * 6 + jj];
            float4 a = *(const float4*)&bufB[(k0 + k) * NB + g * 4];
            ps[0] += a.x * w; ps[1] += a.y * w; ps[2] += a.z * w; ps[3] += a.w * w;
        }
        #pragma unroll
        for (int n = 0; n < 4; ++n) bufA[(s * 6 + jj) * NB + g * 4 + n] = ps[n];
    }
    __syncthreads();
    if (tid < 120) {
        int jj = tid / 20, n = tid % 20;
        float v = bufA[jj * NB + n] + bufA[(6 + jj) * NB + n]
                + bufA[(12 + jj) * NB + n] + bufA[(18 + jj) * NB + n] + ab3[jj];
        out_ids[(n0 + n) * 6 + jj] = v;
        bufC[(32 + jj) * NB + n] = v;
    }
    __syncthreads();

    // ---- nn3 L1: 38 -> 125 (B1 at sW+752) ----
    if (j < 125) {
        float bj = bb1[j];
        acc[0] = bj; acc[1] = bj; acc[2] = bj; acc[3] = bj;
        #pragma unroll 2
        for (int k = 0; k < 38; ++k) {
            float w = sW[752 + k * 125 + j];
            float4 a = *(const float4*)&bufC[k * NB + g * 4];
            acc[0] += a.x * w; acc[1] += a.y * w; acc[2] += a.z * w; acc[3] += a.w * w;
        }
        #pragma unroll
        for (int n = 0; n < 4; ++n) bufA[j * NB + g * 4 + n] = lrelu(acc[n]);
    }
    // prefetch B2 chunk0
    r0 = (tid < 1000) ? ((const float4*)B2)[tid] : make_float4(0.f,0.f,0.f,0.f);
    r1 = (tid < 360)  ? ((const float4*)B2)[tid + 640] : make_float4(0.f,0.f,0.f,0.f);
    __syncthreads();
    if (tid < 1000) ((float4*)sW)[tid] = r0;
    if (tid < 360)  ((float4*)sW)[tid + 640] = r1;
    __syncthreads();

    // ---- nn3 L2: 125 -> 125, chunked dbuf ----
    if (j < 125) { float bj = bb2[j]; acc[0] = bj; acc[1] = bj; acc[2] = bj; acc[3] = bj; }
    for (int c = 0; c < 4; ++c) {
        if (c < 3) {
            int base = (c + 1) * 1000, nf4 = (c + 1 < 3) ? 1000 : 906;
            r0 = (tid < nf4) ? ((const float4*)B2)[base + tid] : make_float4(0.f,0.f,0.f,0.f);
            r1 = (tid + 640 < nf4) ? ((const float4*)B2)[base + tid + 640] : make_float4(0.f,0.f,0.f,0.f);
            if (c + 1 == 3 && tid == 0) rt = B2[15624];
        }
        int nk = (c < 3) ? 32 : 29;
        const float* wbuf = sW + (c & 1) * 4000;
        if (j < 125) {
            const float* arow = &bufA[(c * 32) * NB + g * 4];
            for (int k = 0; k < nk; ++k) {
                float w = wbuf[k * 125 + j];
                float4 a = *(const float4*)&arow[k * NB];
                acc[0] += a.x * w; acc[1] += a.y * w; acc[2] += a.z * w; acc[3] += a.w * w;
            }
        }
        if (c < 3) {
            float* dst = sW + ((c + 1) & 1) * 4000;
            int nf4 = (c + 1 < 3) ? 1000 : 906;
            if (tid < nf4) ((float4*)dst)[tid] = r0;
            if (tid + 640 < nf4) ((float4*)dst)[tid + 640] = r1;
            if (c + 1 == 3 && tid == 0) dst[3624] = rt;
            __syncthreads();
        }
    }
    if (j < 125) {
        #pragma unroll
        for (int n = 0; n < 4; ++n) bufB[j * NB + g * 4 + n] = lrelu(acc[n]);
    }
    __syncthreads();
    // stage B3 (750 -> buf0; chunk3 used buf1)
    if (tid < 187) ((float4*)sW)[tid] = ((const float4*)B3)[tid];
    if (tid == 187) { sW[748] = B3[748]; sW[749] = B3[749]; }
    __syncthreads();

    // ---- nn3 L3: 125 -> 6, 4-way k-split ----
    if (j < 24) {
        int jj = j % 6, s = j / 6;
        int k0 = s * 32, nk = (s < 3) ? 32 : 29;
        float ps[4] = {0.f, 0.f, 0.f, 0.f};
        for (int k = 0; k < nk; ++k) {
            float w = sW[(k0 + k) * 6 + jj];
            float4 a = *(const float4*)&bufB[(k0 + k) * NB + g * 4];
            ps[0] += a.x * w; ps[1] += a.y * w; ps[2] += a.z * w; ps[3] += a.w * w;
        }
        #pragma unroll
        for (int n = 0; n < 4; ++n) bufA[(s * 6 + jj) * NB + g * 4 + n] = ps[n];
    }
    __syncthreads();
    if (tid < 120) {
        int jj = tid / 20, n = tid % 20;
        float v = bufA[jj * NB + n] + bufA[(6 + jj) * NB + n]
                + bufA[(12 + jj) * NB + n] + bufA[(18 + jj) * NB + n] + bb3[jj];
        out_p4[(n0 + n) * 6 + jj] = v;
    }
}

static inline int cdiv(int a, int b) { return (a + b - 1) / b; }

extern "C" void kernel_launch(void* const* d_in, const int* in_sizes, int n_in,
                              void* d_out, int out_size, void* d_ws, size_t ws_size,
                              hipStream_t stream) {
    const float* x        = (const float*)d_in[0];
    const float* ygen_id  = (const float*)d_in[1];
    const float* ygen     = (const float*)d_in[2];
    const float* codebook = (const float*)d_in[3];
    const float* nn1_W1 = (const float*)d_in[4];  const float* nn1_b1 = (const float*)d_in[5];
    const float* nn1_W2 = (const float*)d_in[6];  const float* nn1_b2 = (const float*)d_in[7];
    const float* nn1_W3 = (const float*)d_in[8];  const float* nn1_b3 = (const float*)d_in[9];
    const float* gcn_W  = (const float*)d_in[10]; const float* gcn_b  = (const float*)d_in[11];
    const float* gc_Wrel = (const float*)d_in[12]; const float* gc_brel = (const float*)d_in[13];
    const float* gc_Wroot = (const float*)d_in[14];
    const float* nn2_W1 = (const float*)d_in[15]; const float* nn2_b1 = (const float*)d_in[16];
    const float* nn2_W2 = (const float*)d_in[17]; const float* nn2_b2 = (const float*)d_in[18];
    const float* nn2_W3 = (const float*)d_in[19]; const float* nn2_b3 = (const float*)d_in[20];
    const float* nn3_W1 = (const float*)d_in[21]; const float* nn3_b1 = (const float*)d_in[22];
    const float* nn3_W2 = (const float*)d_in[23]; const float* nn3_b2 = (const float*)d_in[24];
    const float* nn3_W3 = (const float*)d_in[25]; const float* nn3_b3 = (const float*)d_in[26];

    float* out = (float*)d_out;
    float* ws  = (float*)d_ws;

    float* h      = ws + 0;         // 60000
    float* gcn_n  = ws + 60000;     // 160000
    float* agg_n  = ws + 220000;    // 160000
    float* dis_g  = ws + 380000;    // 5000
    _Float16* Mg  = (_Float16*)(ws + 385000);   // 520000 halves
    int* bin_idx  = (int*)(ws + 645000);        // 5000
    int* order    = (int*)(ws + 650000);        // 5000

    nn1_kernel<<<NN / NB, 640, 0, stream>>>(
        x, nn1_W1, nn1_b1, nn1_W2, nn1_b2, nn1_W3, nn1_b3, codebook,
        h, bin_idx);

    scatter_kernel<<<NBINS, 64, 0, stream>>>(bin_idx, order);

    build_kernel<<<NBINS, 256, 0, stream>>>(h, order, Mg, dis_g);

    conv_kernel<<<NBINS * 4, 128, 0, stream>>>(
        Mg, dis_g, h, order, gcn_W, gcn_b, gcn_n, agg_n,
        (const float4*)ygen_id, (const float4*)ygen, (float4*)out);

    nn23_kernel<<<NN / NB, 640, 0, stream>>>(
        gcn_n, agg_n, gc_Wrel, gc_brel, gc_Wroot,
        nn2_W1, nn2_b1, nn2_W2, nn2_b2, nn2_W3, nn2_b3,
        nn3_W1, nn3_b1, nn3_W2, nn3_b2, nn3_W3, nn3_b3,
        out, out + 30000);
}